// Round 6
// baseline (491.265 us; speedup 1.0000x reference)
//
#include <hip/hip_runtime.h>

typedef float        f32x4  __attribute__((ext_vector_type(4)));
typedef float        f32x16 __attribute__((ext_vector_type(16)));
typedef unsigned int u32x4  __attribute__((ext_vector_type(4)));
typedef unsigned int u32x2  __attribute__((ext_vector_type(2)));
typedef int          i32x2  __attribute__((ext_vector_type(2)));
typedef __bf16       bf16x8 __attribute__((ext_vector_type(8)));

#define DEVFN static __device__ __forceinline__

DEVFN unsigned short f2bf(float f){
  unsigned u = __builtin_bit_cast(unsigned, f);
  u += 0x7FFFu + ((u >> 16) & 1u);            // RNE
  return (unsigned short)(u >> 16);
}
DEVFN unsigned cvtpk(float a, float b){       // dst.lo=bf16(a), dst.hi=bf16(b)
  unsigned r;
  asm("v_cvt_pk_bf16_f32 %0, %1, %2" : "=v"(r) : "v"(a), "v"(b));
  return r;
}
DEVFN float exp2_hw(float x){                 // guaranteed single v_exp_f32
  float r;
  asm("v_exp_f32 %0, %1" : "=v"(r) : "v"(x));
  return r;
}
DEVFN bf16x8 as_bf(u32x4 v){ union{u32x4 u; bf16x8 b;} x; x.u=v; return x.b; }

// x' = {x.lo31, y.lo31}; y' = {x.hi31, y.hi31}
DEVFN void plswap(unsigned &x, unsigned &y, int h){
#if __has_builtin(__builtin_amdgcn_permlane32_swap)
  i32x2 r = __builtin_amdgcn_permlane32_swap((int)x, (int)y, false, false);
  x = (unsigned)r[0]; y = (unsigned)r[1];
#else
  unsigned ox = (unsigned)__shfl_xor((int)x, 32);
  unsigned oy = (unsigned)__shfl_xor((int)y, 32);
  unsigned nx = h ? oy : x;
  unsigned ny = h ? y  : ox;
  x = nx; y = ny;
#endif
}

DEVFN void gload16(const char* src, char* lds){
  __builtin_amdgcn_global_load_lds(
      (__attribute__((address_space(1))) void*)src,
      (__attribute__((address_space(3))) void*)lds, 16, 0, 0);
}

constexpr int BB = 16, NQ = 2048, NK = 2048, F = 512, D = 256, FV = 512;

// ---------------- projection + row l2norm ---------------- (unchanged, known-good)
template<int KD, int ND, bool TR>
__global__ __launch_bounds__(256,2) void proj_kernel(const float* __restrict__ X,
                                                     const float* __restrict__ W,
                                                     unsigned short* __restrict__ Y,
                                                     float scale)
{
  constexpr int NW = ND/4;
  constexpr int AF = TR ? 8 : 2;
  constexpr int BF = TR ? 2 : NW/16;
  __shared__ __align__(16) char xsm[32*80];
  __shared__ __align__(16) char wsm[ND*80];
  __shared__ float wsum[4][32];
  const int tid = threadIdx.x;
  const int lane = tid & 63;
  const int wid = tid >> 6;
  const int q16 = lane & 15;
  const int g = lane >> 4;
  const int row0 = blockIdx.x * 32;
  const int rX = tid >> 3, cX = (tid & 7) * 4;

  f32x4 z4 = {0.f,0.f,0.f,0.f};
  f32x4 acc[AF][BF];
  #pragma unroll
  for (int i=0;i<AF;i++){
    #pragma unroll
    for (int j=0;j<BF;j++) acc[i][j] = z4;
  }

  for (int k0 = 0; k0 < KD; k0 += 32){
    {
      f32x4 v = *(const f32x4*)(X + (size_t)(row0+rX)*KD + k0 + cX);
      u32x2 p; p[0]=cvtpk(v[0],v[1]); p[1]=cvtpk(v[2],v[3]);
      *(u32x2*)(xsm + rX*80 + cX*2) = p;
    }
    #pragma unroll
    for (int j=0;j<ND/32;j++){
      int r = j*32 + rX;
      f32x4 v = *(const f32x4*)(W + (size_t)r*KD + k0 + cX);
      u32x2 p; p[0]=cvtpk(v[0],v[1]); p[1]=cvtpk(v[2],v[3]);
      *(u32x2*)(wsm + r*80 + cX*2) = p;
    }
    __syncthreads();
    if constexpr (!TR){
      bf16x8 a[2], bb[BF];
      #pragma unroll
      for (int mi=0;mi<2;mi++)  a[mi]  = as_bf(*(const u32x4*)(xsm + (16*mi+q16)*80 + g*16));
      #pragma unroll
      for (int ni=0;ni<BF;ni++) bb[ni] = as_bf(*(const u32x4*)(wsm + (wid*NW + 16*ni + q16)*80 + g*16));
      #pragma unroll
      for (int mi=0;mi<2;mi++){
        #pragma unroll
        for (int ni=0;ni<BF;ni++)
          acc[mi][ni] = __builtin_amdgcn_mfma_f32_16x16x32_bf16(a[mi], bb[ni], acc[mi][ni], 0,0,0);
      }
    } else {
      bf16x8 a[8], bb[2];
      #pragma unroll
      for (int ai=0;ai<8;ai++) a[ai] = as_bf(*(const u32x4*)(wsm + (wid*NW + 16*ai + q16)*80 + g*16));
      #pragma unroll
      for (int ci=0;ci<2;ci++) bb[ci] = as_bf(*(const u32x4*)(xsm + (16*ci+q16)*80 + g*16));
      #pragma unroll
      for (int ai=0;ai<8;ai++){
        #pragma unroll
        for (int ci=0;ci<2;ci++)
          acc[ai][ci] = __builtin_amdgcn_mfma_f32_16x16x32_bf16(a[ai], bb[ci], acc[ai][ci], 0,0,0);
      }
    }
    __syncthreads();
  }

  if constexpr (!TR){
    float part[2][4];
    #pragma unroll
    for (int mi=0;mi<2;mi++){
      #pragma unroll
      for (int r=0;r<4;r++){
        float s=0.f;
        #pragma unroll
        for (int ni=0;ni<BF;ni++){ float v=acc[mi][ni][r]; s += v*v; }
        part[mi][r]=s;
      }
    }
    #pragma unroll
    for (int m=1;m<16;m<<=1){
      #pragma unroll
      for (int mi=0;mi<2;mi++){
        #pragma unroll
        for (int r=0;r<4;r++) part[mi][r] += __shfl_xor(part[mi][r], m);
      }
    }
    if (q16 == 0){
      #pragma unroll
      for (int mi=0;mi<2;mi++){
        #pragma unroll
        for (int r=0;r<4;r++) wsum[wid][16*mi + 4*g + r] = part[mi][r];
      }
    }
    __syncthreads();
    #pragma unroll
    for (int mi=0;mi<2;mi++){
      #pragma unroll
      for (int r=0;r<4;r++){
        int m = 16*mi + 4*g + r;
        float tot = wsum[0][m]+wsum[1][m]+wsum[2][m]+wsum[3][m];
        float inv = scale / fmaxf(sqrtf(tot), 1e-12f);
        #pragma unroll
        for (int ni=0;ni<BF;ni++){
          int col = wid*NW + 16*ni + q16;
          Y[(size_t)(row0+m)*ND + col] = f2bf(acc[mi][ni][r]*inv);
        }
      }
    }
  } else {
    float pp[2];
    #pragma unroll
    for (int ci=0;ci<2;ci++){
      float s=0.f;
      #pragma unroll
      for (int ai=0;ai<8;ai++){
        #pragma unroll
        for (int r=0;r<4;r++){ float v=acc[ai][ci][r]; s += v*v; }
      }
      pp[ci]=s;
    }
    #pragma unroll
    for (int ci=0;ci<2;ci++){
      pp[ci] += __shfl_xor(pp[ci],16);
      pp[ci] += __shfl_xor(pp[ci],32);
    }
    if (lane < 16){ wsum[wid][lane] = pp[0]; wsum[wid][16+lane] = pp[1]; }
    __syncthreads();
    #pragma unroll
    for (int ci=0;ci<2;ci++){
      int m = 16*ci + q16;
      float tot = wsum[0][m]+wsum[1][m]+wsum[2][m]+wsum[3][m];
      float inv = scale / fmaxf(sqrtf(tot), 1e-12f);
      int grow = row0 + m;
      int b = grow >> 11;
      int kv = grow & 2047;
      #pragma unroll
      for (int ai=0;ai<8;ai++){
        #pragma unroll
        for (int r=0;r<4;r++){
          int n = wid*NW + 16*ai + 4*g + r;
          Y[((size_t)b*FV + n)*NK + kv] = f2bf(acc[ai][ci][r]*inv);
        }
      }
    }
  }
}

// ---------------- fused attention (v6: cross-tile pipeline) ----------------
// 256 blocks = 16 b x 16 qblk(128 q). 512 thr = 8 waves; wave = (qs, fvh).
// Per iter t: stage(t+2) -> exp(S(t)) -> QK(t+1) (K dbuf) -> cvt/swap -> PV(t)
// (V triple-buffer). One barrier/tile; all buffer indices compile-time (unroll 6).
__global__ __launch_bounds__(512,2) void attn_kernel(const float* __restrict__ query,
    const unsigned short* __restrict__ wq, const unsigned short* __restrict__ wk,
    const unsigned short* __restrict__ wvt, float* __restrict__ out)
{
  // K dbuf 2x16K @0 | V tbuf 3x32K @32768 ; total 128KB. Epilogue reuses 64KB.
  __shared__ __align__(16) char smem[131072];
  const int tid = threadIdx.x, lane = tid & 63, wid = tid >> 6;
  const int l31 = lane & 31, h = lane >> 5;
  const int qs = wid & 3, fvh = wid >> 2;
  const int bid = blockIdx.x;
  const int lb = (bid & 7)*32 + (bid >> 3);   // XCD chunk swizzle, 256 = 8*32 bijective
  const int b = lb >> 4;
  const int qblk = lb & 15;
  const int q0 = qblk*128;

  const char* wk_b  = (const char*)(wk  + (size_t)b*NK*D);
  const char* wvt_b = (const char*)(wvt + (size_t)b*FV*NK);
  // staging source bases (lane-resolved)
  const char* ksrc  = wk_b + (size_t)l31*512 + wid*64 + h*16;          // frags 2w, 2w+1
  const char* vsrcA = wvt_b + (size_t)(wid*2)*131072 + (size_t)l31*4096 + h*16;
  const char* vsrcB = vsrcA + 131072;

  #define STAGE_K(T, C) do{                                           \
    char* kb_ = smem + (C)*16384;                                     \
    size_t ko_ = (size_t)(T)*16384;                                   \
    gload16(ksrc + ko_,      kb_ + (2*wid  )*1024);                   \
    gload16(ksrc + ko_ + 32, kb_ + (2*wid+1)*1024);                   \
  }while(0)
  #define STAGE_V(T, C) do{                                           \
    char* vb_ = smem + 32768 + (C)*32768;                             \
    size_t vo_ = (size_t)(T)*64;                                      \
    gload16(vsrcA + vo_,      vb_ + (4*wid  )*1024);                  \
    gload16(vsrcA + vo_ + 32, vb_ + (4*wid+1)*1024);                  \
    gload16(vsrcB + vo_,      vb_ + (4*wid+2)*1024);                  \
    gload16(vsrcB + vo_ + 32, vb_ + (4*wid+3)*1024);                  \
  }while(0)

  STAGE_K(0, 0);
  STAGE_K(1, 1);
  STAGE_V(0, 0);
  STAGE_V(1, 1);

  // Q hoist for slice qs: B-frags [16 c][32 q], lane: q=l31, d = c*16 + h*8 ..+8
  bf16x8 qf[16];
  {
    const char* qb = (const char*)(wq + ((size_t)b*NQ + q0 + qs*32 + l31)*D);
    #pragma unroll
    for (int c=0;c<16;c++) qf[c] = as_bf(*(const u32x4*)(qb + c*32 + h*16));
  }

  f32x16 z16;
  #pragma unroll
  for (int i=0;i<16;i++) z16[i]=0.f;
  f32x16 o[8];
  #pragma unroll
  for (int i=0;i<8;i++) o[i]=z16;
  float ssum = 0.f;

  __syncthreads();

  // prologue QK(0) -> S
  f32x16 S = z16;
  __builtin_amdgcn_s_setprio(1);
  #pragma unroll
  for (int c=0;c<16;c++){
    bf16x8 a = as_bf(*(const u32x4*)(smem + c*1024 + lane*16));
    S = __builtin_amdgcn_mfma_f32_32x32x16_bf16(a, qf[c], S, 0,0,0);
  }
  __builtin_amdgcn_s_setprio(0);
  __syncthreads();   // protect kbuf0 from iter-0 staging until all waves did QK(0)

  #define BODY(KK) do{                                                              \
    const int T = tt + (KK);                                                        \
    if (T < 62){ STAGE_K(T+2, (KK)&1); STAGE_V(T+2, ((KK)+2)%3); }                  \
    float p[16];                                                                    \
    _Pragma("unroll")                                                               \
    for (int r=0;r<16;r++) p[r] = exp2_hw(S[r]);                                    \
    float s2[8];                                                                    \
    _Pragma("unroll")                                                               \
    for (int j=0;j<8;j++) s2[j] = p[2*j] + p[2*j+1];                                \
    float s4a = (s2[0]+s2[1]) + (s2[2]+s2[3]);                                      \
    float s4b = (s2[4]+s2[5]) + (s2[6]+s2[7]);                                      \
    ssum += s4a + s4b;                                                              \
    if (T < 63){  /* QK(T+1), independent of softmax(T)/PV(T) */                    \
      const char* kb = smem + (((KK)+1)&1)*16384;                                   \
      f32x16 Sn = z16;                                                              \
      __builtin_amdgcn_s_setprio(1);                                                \
      _Pragma("unroll")                                                             \
      for (int c=0;c<16;c++){                                                       \
        bf16x8 a = as_bf(*(const u32x4*)(kb + c*1024 + lane*16));                   \
        Sn = __builtin_amdgcn_mfma_f32_32x32x16_bf16(a, qf[c], Sn, 0,0,0);          \
      }                                                                             \
      __builtin_amdgcn_s_setprio(0);                                                \
      S = Sn;                                                                       \
    }                                                                               \
    unsigned pk[8];                                                                 \
    _Pragma("unroll")                                                               \
    for (int j=0;j<8;j++) pk[j] = cvtpk(p[2*j], p[2*j+1]);                          \
    plswap(pk[0], pk[2], h);  plswap(pk[1], pk[3], h);                              \
    plswap(pk[4], pk[6], h);  plswap(pk[5], pk[7], h);                              \
    u32x4 w0 = {pk[0],pk[1],pk[2],pk[3]}, w1 = {pk[4],pk[5],pk[6],pk[7]};           \
    bf16x8 pf0 = as_bf(w0), pf1 = as_bf(w1);                                        \
    const char* vb = smem + 32768 + ((KK)%3)*32768;                                 \
    __builtin_amdgcn_s_setprio(1);                                                  \
    _Pragma("unroll")                                                               \
    for (int u=0;u<8;u++){                                                          \
      bf16x8 a0 = as_bf(*(const u32x4*)(vb + ((fvh*8+u)*2  )*1024 + lane*16));      \
      o[u] = __builtin_amdgcn_mfma_f32_32x32x16_bf16(a0, pf0, o[u], 0,0,0);         \
      bf16x8 a1 = as_bf(*(const u32x4*)(vb + ((fvh*8+u)*2+1)*1024 + lane*16));      \
      o[u] = __builtin_amdgcn_mfma_f32_32x32x16_bf16(a1, pf1, o[u], 0,0,0);         \
    }                                                                               \
    __builtin_amdgcn_s_setprio(0);                                                  \
    __syncthreads();                                                                \
  }while(0)

  int tt = 0;
  for (; tt < 60; tt += 6){
    BODY(0); BODY(1); BODY(2); BODY(3); BODY(4); BODY(5);
  }
  // tail: tt = 60, T = 60..63 (parities match since 60 % 6 == 0)
  BODY(0); BODY(1); BODY(2); BODY(3);
  #undef BODY
  #undef STAGE_K
  #undef STAGE_V

  // epilogue: scale by 1/ssum, transpose via LDS [32q][128fv] x2, +query, store.
  ssum += __shfl_xor(ssum, 32);
  const float inv = 1.f/ssum;
  #pragma unroll
  for (int i=0;i<8;i++){
    #pragma unroll
    for (int r=0;r<16;r++) o[i][r] *= inv;
  }

  char* wsc = smem + qs*16384;
  union U16 { f32x16 v; f32x4 q4[4]; };
  const int swz = (l31 & 7) << 4;
  #pragma unroll
  for (int phase=0; phase<2; ++phase){
    if (fvh == phase){
      #pragma unroll
      for (int hf=0; hf<2; ++hf){
        #pragma unroll
        for (int fc2=0; fc2<4; ++fc2){
          U16 u; u.v = o[hf*4+fc2];
          #pragma unroll
          for (int k=0;k<4;k++){
            *(f32x4*)(wsc + l31*512 + ((fc2*128 + k*32 + h*16) ^ swz)) = u.q4[k];
          }
        }
        #pragma unroll
        for (int p2=0;p2<16;p2++){
          int qr = p2*2 + h;
          f32x4 v = *(const f32x4*)(wsc + qr*512 + ((l31*16) ^ ((qr&7)<<4)));
          size_t row = (size_t)b*NQ + q0 + qs*32 + qr;
          int col = fvh*256 + hf*128 + l31*4;
          f32x4 qv = *(const f32x4*)(query + row*F + col);
          #pragma unroll
          for (int e=0;e<4;e++) v[e] += qv[e];
          *(f32x4*)(out + row*F + col) = v;
        }
      }
    }
    __syncthreads();
  }
}

extern "C" void kernel_launch(void* const* d_in, const int* in_sizes, int n_in,
                              void* d_out, int out_size, void* d_ws, size_t ws_size,
                              hipStream_t stream)
{
  const float* query = (const float*)d_in[0];
  const float* key   = (const float*)d_in[1];
  const float* value = (const float*)d_in[2];
  const float* WQ    = (const float*)d_in[3];
  const float* WK    = (const float*)d_in[4];
  const float* WV    = (const float*)d_in[5];
  float* out = (float*)d_out;

  unsigned short* wq  = (unsigned short*)d_ws;              // [B*NQ][256] bf16, 16MB
  unsigned short* wk  = wq + (size_t)BB*NQ*D;               // [B*NK][256] bf16, 16MB
  unsigned short* wvt = wk + (size_t)BB*NK*D;               // [B][512][NK] bf16, 32MB

  const float c1 = 0.0625f * 1.4426950408889634f;           // temp * log2(e)
  dim3 blk(256);
  proj_kernel<512,256,false><<<1024, blk, 0, stream>>>(query, WQ, wq, c1);
  proj_kernel<256,256,false><<<1024, blk, 0, stream>>>(key,   WK, wk, 1.0f);
  proj_kernel<256,512,true ><<<1024, blk, 0, stream>>>(value, WV, wvt, 1.0f);
  attn_kernel<<<256, dim3(512), 0, stream>>>(query, wq, wk, wvt, out);
}

// Round 7
// 195.702 us; speedup vs baseline: 2.5103x; 2.5103x over previous
//
#include <hip/hip_runtime.h>

typedef float        f32x4  __attribute__((ext_vector_type(4)));
typedef float        f32x16 __attribute__((ext_vector_type(16)));
typedef unsigned int u32x4  __attribute__((ext_vector_type(4)));
typedef unsigned int u32x2  __attribute__((ext_vector_type(2)));
typedef int          i32x2  __attribute__((ext_vector_type(2)));
typedef __bf16       bf16x8 __attribute__((ext_vector_type(8)));

#define DEVFN static __device__ __forceinline__

DEVFN unsigned cvtpk(float a, float b){       // bf16 pack (proj staging)
  unsigned r;
  asm("v_cvt_pk_bf16_f32 %0, %1, %2" : "=v"(r) : "v"(a), "v"(b));
  return r;
}
DEVFN float exp2_hw(float x){
  float r;
  asm("v_exp_f32 %0, %1" : "=v"(r) : "v"(x));
  return r;
}
DEVFN bf16x8 as_bf(u32x4 v){ union{u32x4 u; bf16x8 b;} x; x.u=v; return x.b; }

DEVFN unsigned char f2fp8(float v){           // scalar f32 -> e4m3 byte
  int r = __builtin_amdgcn_cvt_pk_fp8_f32(v, v, 0, false);
  return (unsigned char)(r & 0xff);
}
DEVFN unsigned pk4_fp8(float a, float b, float c, float d){  // bytes [a,b,c,d]
  int r = __builtin_amdgcn_cvt_pk_fp8_f32(a, b, 0, false);
  r = __builtin_amdgcn_cvt_pk_fp8_f32(c, d, r, true);
  return (unsigned)r;
}
DEVFN long mk64(unsigned lo, unsigned hi){
  return (long)(((unsigned long long)hi << 32) | lo);
}

// x' = {x.lo31, y.lo31-as-hi...}: exchanges x's high 32 lanes with y's low 32 lanes
DEVFN void plswap(unsigned &x, unsigned &y, int h){
#if __has_builtin(__builtin_amdgcn_permlane32_swap)
  i32x2 r = __builtin_amdgcn_permlane32_swap((int)x, (int)y, false, false);
  x = (unsigned)r[0]; y = (unsigned)r[1];
#else
  unsigned ox = (unsigned)__shfl_xor((int)x, 32);
  unsigned oy = (unsigned)__shfl_xor((int)y, 32);
  unsigned nx = h ? oy : x;
  unsigned ny = h ? y  : ox;
  x = nx; y = ny;
#endif
}

DEVFN void gload16(const char* src, char* lds){
  __builtin_amdgcn_global_load_lds(
      (__attribute__((address_space(1))) void*)src,
      (__attribute__((address_space(3))) void*)lds, 16, 0, 0);
}

constexpr int BB = 16, NQ = 2048, NK = 2048, F = 512, D = 256, FV = 512;

// ---------------- projection + row l2norm -> fp8 outputs ----------------
// Y[m][n] = scale * l2norm_rows( X[m][:] . W[n][:] ), 32 rows/block.
// MODE 0: row-major fp8 [row][ND] (wq)
// MODE 1: K frag-image  [b][kt][u][lane][16] (wk)
// MODE 2: V frag-image  [b][kt][fvh][u][lane][16], transposed (wv)
template<int KD, int ND, int MODE>
__global__ __launch_bounds__(256,2) void proj_kernel(const float* __restrict__ X,
                                                     const float* __restrict__ W,
                                                     unsigned char* __restrict__ Y,
                                                     float scale)
{
  constexpr bool TR = (MODE == 2);
  constexpr int NW = ND/4;
  constexpr int AF = TR ? 8 : 2;
  constexpr int BF = TR ? 2 : NW/16;
  __shared__ __align__(16) char xsm[32*80];
  __shared__ __align__(16) char wsm[ND*80];
  __shared__ float wsum[4][32];
  const int tid = threadIdx.x;
  const int lane = tid & 63;
  const int wid = tid >> 6;
  const int q16 = lane & 15;
  const int g = lane >> 4;
  const int row0 = blockIdx.x * 32;
  const int rX = tid >> 3, cX = (tid & 7) * 4;

  f32x4 z4 = {0.f,0.f,0.f,0.f};
  f32x4 acc[AF][BF];
  #pragma unroll
  for (int i=0;i<AF;i++){
    #pragma unroll
    for (int j=0;j<BF;j++) acc[i][j] = z4;
  }

  for (int k0 = 0; k0 < KD; k0 += 32){
    {
      f32x4 v = *(const f32x4*)(X + (size_t)(row0+rX)*KD + k0 + cX);
      u32x2 p; p[0]=cvtpk(v[0],v[1]); p[1]=cvtpk(v[2],v[3]);
      *(u32x2*)(xsm + rX*80 + cX*2) = p;
    }
    #pragma unroll
    for (int j=0;j<ND/32;j++){
      int r = j*32 + rX;
      f32x4 v = *(const f32x4*)(W + (size_t)r*KD + k0 + cX);
      u32x2 p; p[0]=cvtpk(v[0],v[1]); p[1]=cvtpk(v[2],v[3]);
      *(u32x2*)(wsm + r*80 + cX*2) = p;
    }
    __syncthreads();
    if constexpr (!TR){
      bf16x8 a[2], bb[BF];
      #pragma unroll
      for (int mi=0;mi<2;mi++)  a[mi]  = as_bf(*(const u32x4*)(xsm + (16*mi+q16)*80 + g*16));
      #pragma unroll
      for (int ni=0;ni<BF;ni++) bb[ni] = as_bf(*(const u32x4*)(wsm + (wid*NW + 16*ni + q16)*80 + g*16));
      #pragma unroll
      for (int mi=0;mi<2;mi++){
        #pragma unroll
        for (int ni=0;ni<BF;ni++)
          acc[mi][ni] = __builtin_amdgcn_mfma_f32_16x16x32_bf16(a[mi], bb[ni], acc[mi][ni], 0,0,0);
      }
    } else {
      bf16x8 a[8], bb[2];
      #pragma unroll
      for (int ai=0;ai<8;ai++) a[ai] = as_bf(*(const u32x4*)(wsm + (wid*NW + 16*ai + q16)*80 + g*16));
      #pragma unroll
      for (int ci=0;ci<2;ci++) bb[ci] = as_bf(*(const u32x4*)(xsm + (16*ci+q16)*80 + g*16));
      #pragma unroll
      for (int ai=0;ai<8;ai++){
        #pragma unroll
        for (int ci=0;ci<2;ci++)
          acc[ai][ci] = __builtin_amdgcn_mfma_f32_16x16x32_bf16(a[ai], bb[ci], acc[ai][ci], 0,0,0);
      }
    }
    __syncthreads();
  }

  if constexpr (!TR){
    float part[2][4];
    #pragma unroll
    for (int mi=0;mi<2;mi++){
      #pragma unroll
      for (int r=0;r<4;r++){
        float s=0.f;
        #pragma unroll
        for (int ni=0;ni<BF;ni++){ float v=acc[mi][ni][r]; s += v*v; }
        part[mi][r]=s;
      }
    }
    #pragma unroll
    for (int m=1;m<16;m<<=1){
      #pragma unroll
      for (int mi=0;mi<2;mi++){
        #pragma unroll
        for (int r=0;r<4;r++) part[mi][r] += __shfl_xor(part[mi][r], m);
      }
    }
    if (q16 == 0){
      #pragma unroll
      for (int mi=0;mi<2;mi++){
        #pragma unroll
        for (int r=0;r<4;r++) wsum[wid][16*mi + 4*g + r] = part[mi][r];
      }
    }
    __syncthreads();
    #pragma unroll
    for (int mi=0;mi<2;mi++){
      #pragma unroll
      for (int r=0;r<4;r++){
        int m = 16*mi + 4*g + r;
        float tot = wsum[0][m]+wsum[1][m]+wsum[2][m]+wsum[3][m];
        float inv = scale / fmaxf(sqrtf(tot), 1e-12f);
        int row = row0 + m;
        #pragma unroll
        for (int ni=0;ni<BF;ni++){
          int col = wid*NW + 16*ni + q16;
          unsigned char vb = f2fp8(acc[mi][ni][r]*inv);
          if constexpr (MODE == 0){
            Y[(size_t)row*ND + col] = vb;
          } else {
            int b2 = row >> 11, kv = row & 2047;
            int kt = kv >> 5, mm = kv & 31;
            int u = col >> 5, dd = col & 31;
            int s = ((dd>>4)<<3) | (dd&7);
            int l = mm + ((dd>>3)&1)*32;
            Y[((((size_t)b2*64 + kt)*8 + u)*64 + l)*16 + s] = vb;
          }
        }
      }
    }
  } else {
    float pp[2];
    #pragma unroll
    for (int ci=0;ci<2;ci++){
      float s=0.f;
      #pragma unroll
      for (int ai=0;ai<8;ai++){
        #pragma unroll
        for (int r=0;r<4;r++){ float v=acc[ai][ci][r]; s += v*v; }
      }
      pp[ci]=s;
    }
    #pragma unroll
    for (int ci=0;ci<2;ci++){
      pp[ci] += __shfl_xor(pp[ci],16);
      pp[ci] += __shfl_xor(pp[ci],32);
    }
    if (lane < 16){ wsum[wid][lane] = pp[0]; wsum[wid][16+lane] = pp[1]; }
    __syncthreads();
    #pragma unroll
    for (int ci=0;ci<2;ci++){
      int m = 16*ci + q16;
      float tot = wsum[0][m]+wsum[1][m]+wsum[2][m]+wsum[3][m];
      float inv = scale / fmaxf(sqrtf(tot), 1e-12f);
      int grow = row0 + m;
      int b2 = grow >> 11;
      int kv = grow & 2047;
      int kt = kv >> 5, kl = kv & 31;
      int s = ((kl>>4)<<3) | (kl&7);
      int lofs = ((kl>>3)&1)*32;
      #pragma unroll
      for (int ai=0;ai<8;ai++){
        #pragma unroll
        for (int r=0;r<4;r++){
          int n = wid*NW + 16*ai + 4*g + r;
          int fvh = n >> 8, u = (n>>5)&7, mm = n & 31;
          unsigned char vb = f2fp8(acc[ai][ci][r]*inv);
          Y[(((((size_t)b2*64 + kt)*2 + fvh)*8 + u)*64 + (mm + lofs))*16 + s] = vb;
        }
      }
    }
  }
}

// ---------------- fused attention (v7: fp8, R5 schedule) ----------------
// 256 blocks = 16 b x 16 qblk(128 q). 512 thr = 8 waves; wave = (qs, fvh):
// 32 q rows, 256 fv cols. kv-tile 32, dbuf fragpair-major LDS (48KB),
// 1 barrier/tile. mfma_f32_32x32x16_fp8_fp8; P built in-register
// (cvt_pk_fp8 + permlane32_swap). S_raw = 64*cos (inputs scaled x8).
__global__ __launch_bounds__(512,2) void attn_kernel(const float* __restrict__ query,
    const unsigned char* __restrict__ wq8, const unsigned char* __restrict__ k8,
    const unsigned char* __restrict__ v8, float* __restrict__ out)
{
  // K dbuf 2x8K @0 | V dbuf 2x16K @16384 (48K) ; epilogue reuses 64K.
  __shared__ __align__(16) char smem[65536];
  const int tid = threadIdx.x, lane = tid & 63, wid = tid >> 6;
  const int l31 = lane & 31, h = lane >> 5;
  const int qs = wid & 3, fvh = wid >> 2;
  const int bid = blockIdx.x;
  const int lb = (bid & 7)*32 + (bid >> 3);   // XCD chunk swizzle, 256 = 8*32 bijective
  const int b = lb >> 4;
  const int qblk = lb & 15;
  const int q0 = qblk*128;

  const char* ksrc = (const char*)(k8 + (size_t)b*524288) + lane*16;
  const char* vsrc = (const char*)(v8 + (size_t)b*1048576) + lane*16;

  #define STAGE(T, CUR) do{                                                       \
    gload16(ksrc + (size_t)(T)*8192  + wid*1024,                                  \
            smem + (CUR)*8192 + wid*1024);                                        \
    gload16(vsrc + (size_t)(T)*16384 + (2*wid  )*1024,                            \
            smem + 16384 + (CUR)*16384 + (2*wid  )*1024);                         \
    gload16(vsrc + (size_t)(T)*16384 + (2*wid+1)*1024,                            \
            smem + 16384 + (CUR)*16384 + (2*wid+1)*1024);                         \
  }while(0)

  STAGE(0, 0);

  // Q hoist: fp8 B-frags [16 c][32 q]: lane q=l31, bytes d = c*16 + h*8 ..+8
  unsigned long long qf[16];
  {
    const unsigned char* qb = wq8 + ((size_t)b*NQ + q0 + qs*32 + l31)*D;
    #pragma unroll
    for (int c=0;c<16;c++) qf[c] = *(const unsigned long long*)(qb + c*16 + h*8);
  }

  f32x16 z16;
  #pragma unroll
  for (int i=0;i<16;i++) z16[i]=0.f;
  f32x16 o[8];
  #pragma unroll
  for (int i=0;i<8;i++) o[i]=z16;
  float ssum = 0.f;
  const float c2 = 0.0625f * 1.4426950408889634f / 64.0f;   // temp*log2e / (8*8)

  __syncthreads();

  #define BODY(T, CUR) do{                                                          \
    if ((T) < 63) STAGE((T)+1, (CUR)^1);                                            \
    const char* kb = smem + (CUR)*8192;                                             \
    const char* vb = smem + 16384 + (CUR)*16384;                                    \
    f32x16 S = z16;                                                                 \
    __builtin_amdgcn_s_setprio(1);                                                  \
    _Pragma("unroll")                                                               \
    for (int u=0;u<8;u++){                                                          \
      u32x4 kk = *(const u32x4*)(kb + u*1024 + lane*16);                            \
      S = __builtin_amdgcn_mfma_f32_32x32x16_fp8_fp8(mk64(kk[0],kk[1]),             \
            (long)qf[2*u],   S, 0,0,0);                                             \
      S = __builtin_amdgcn_mfma_f32_32x32x16_fp8_fp8(mk64(kk[2],kk[3]),             \
            (long)qf[2*u+1], S, 0,0,0);                                             \
    }                                                                               \
    __builtin_amdgcn_s_setprio(0);                                                  \
    float p[16];                                                                    \
    _Pragma("unroll")                                                               \
    for (int r=0;r<16;r++) p[r] = exp2_hw(S[r]*c2);                                 \
    float s2[8];                                                                    \
    _Pragma("unroll")                                                               \
    for (int j=0;j<8;j++) s2[j] = p[2*j] + p[2*j+1];                                \
    float s4a = (s2[0]+s2[1]) + (s2[2]+s2[3]);                                      \
    float s4b = (s2[4]+s2[5]) + (s2[6]+s2[7]);                                      \
    ssum += s4a + s4b;                                                              \
    unsigned d0 = pk4_fp8(p[0],p[1],p[2],p[3]);     /* kv 4h+0..3   */              \
    unsigned d1 = pk4_fp8(p[4],p[5],p[6],p[7]);     /* kv 8+4h..    */              \
    unsigned d2 = pk4_fp8(p[8],p[9],p[10],p[11]);   /* kv 16+4h..   */              \
    unsigned d3 = pk4_fp8(p[12],p[13],p[14],p[15]); /* kv 24+4h..   */              \
    plswap(d0, d1, h);  plswap(d2, d3, h);                                          \
    long P0 = mk64(d0, d1);   /* chunk0: kv 8h..8h+7  */                            \
    long P1 = mk64(d2, d3);   /* chunk1: kv 16+8h..   */                            \
    __builtin_amdgcn_s_setprio(1);                                                  \
    _Pragma("unroll")                                                               \
    for (int u=0;u<8;u++){                                                          \
      u32x4 vv = *(const u32x4*)(vb + (fvh*8+u)*1024 + lane*16);                    \
      o[u] = __builtin_amdgcn_mfma_f32_32x32x16_fp8_fp8(mk64(vv[0],vv[1]), P0,      \
                                                        o[u], 0,0,0);               \
      o[u] = __builtin_amdgcn_mfma_f32_32x32x16_fp8_fp8(mk64(vv[2],vv[3]), P1,      \
                                                        o[u], 0,0,0);               \
    }                                                                               \
    __builtin_amdgcn_s_setprio(0);                                                  \
    __syncthreads();                                                                \
  }while(0)

  for (int tt = 0; tt < 64; tt += 2){
    BODY(tt,   0);
    BODY(tt+1, 1);
  }
  #undef BODY
  #undef STAGE

  // epilogue: scale by 1/(8*ssum) (V scaled x8), transpose via LDS, +query, store.
  ssum += __shfl_xor(ssum, 32);
  const float inv = 1.f/(8.f*ssum);
  #pragma unroll
  for (int i=0;i<8;i++){
    #pragma unroll
    for (int r=0;r<16;r++) o[i][r] *= inv;
  }

  char* wsc = smem + qs*16384;
  union U16 { f32x16 v; f32x4 q4[4]; };
  const int swz = (l31 & 7) << 4;
  #pragma unroll
  for (int phase=0; phase<2; ++phase){
    if (fvh == phase){
      #pragma unroll
      for (int hf=0; hf<2; ++hf){
        #pragma unroll
        for (int fc2=0; fc2<4; ++fc2){
          U16 u; u.v = o[hf*4+fc2];
          #pragma unroll
          for (int k=0;k<4;k++){
            *(f32x4*)(wsc + l31*512 + ((fc2*128 + k*32 + h*16) ^ swz)) = u.q4[k];
          }
        }
        #pragma unroll
        for (int p2=0;p2<16;p2++){
          int qr = p2*2 + h;
          f32x4 v = *(const f32x4*)(wsc + qr*512 + ((l31*16) ^ ((qr&7)<<4)));
          size_t row = (size_t)b*NQ + q0 + qs*32 + qr;
          int col = fvh*256 + hf*128 + l31*4;
          f32x4 qv = *(const f32x4*)(query + row*F + col);
          #pragma unroll
          for (int e=0;e<4;e++) v[e] += qv[e];
          *(f32x4*)(out + row*F + col) = v;
        }
      }
    }
    __syncthreads();
  }
}

extern "C" void kernel_launch(void* const* d_in, const int* in_sizes, int n_in,
                              void* d_out, int out_size, void* d_ws, size_t ws_size,
                              hipStream_t stream)
{
  const float* query = (const float*)d_in[0];
  const float* key   = (const float*)d_in[1];
  const float* value = (const float*)d_in[2];
  const float* WQ    = (const float*)d_in[3];
  const float* WK    = (const float*)d_in[4];
  const float* WV    = (const float*)d_in[5];
  float* out = (float*)d_out;

  unsigned char* wq8 = (unsigned char*)d_ws;                 // [B*NQ][256] fp8, 8MB
  unsigned char* k8  = wq8 + (size_t)BB*NQ*D;                // K frag-image, 8MB
  unsigned char* v8  = k8  + (size_t)BB*NK*D;                // V frag-image, 8MB

  dim3 blk(256);
  proj_kernel<512,256,0><<<1024, blk, 0, stream>>>(query, WQ, wq8, 8.0f);
  proj_kernel<256,256,1><<<1024, blk, 0, stream>>>(key,   WK, k8,  8.0f);
  proj_kernel<256,512,2><<<1024, blk, 0, stream>>>(value, WV, v8,  8.0f);
  attn_kernel<<<256, dim3(512), 0, stream>>>(query, wq8, k8, v8, out);
}

// Round 8
// 189.239 us; speedup vs baseline: 2.5960x; 1.0342x over previous
//
#include <hip/hip_runtime.h>

typedef float        f32x4  __attribute__((ext_vector_type(4)));
typedef float        f32x16 __attribute__((ext_vector_type(16)));
typedef unsigned int u32x4  __attribute__((ext_vector_type(4)));
typedef unsigned int u32x2  __attribute__((ext_vector_type(2)));
typedef int          i32x2  __attribute__((ext_vector_type(2)));
typedef __bf16       bf16x8 __attribute__((ext_vector_type(8)));

#define DEVFN static __device__ __forceinline__

DEVFN unsigned cvtpk(float a, float b){       // bf16 pack (proj staging)
  unsigned r;
  asm("v_cvt_pk_bf16_f32 %0, %1, %2" : "=v"(r) : "v"(a), "v"(b));
  return r;
}
DEVFN float exp2_hw(float x){
  float r;
  asm("v_exp_f32 %0, %1" : "=v"(r) : "v"(x));
  return r;
}
DEVFN bf16x8 as_bf(u32x4 v){ union{u32x4 u; bf16x8 b;} x; x.u=v; return x.b; }

DEVFN unsigned char f2fp8(float v){           // scalar f32 -> e4m3 byte
  int r = __builtin_amdgcn_cvt_pk_fp8_f32(v, v, 0, false);
  return (unsigned char)(r & 0xff);
}
DEVFN unsigned pk4_fp8(float a, float b, float c, float d){  // bytes [a,b,c,d]
  int r = __builtin_amdgcn_cvt_pk_fp8_f32(a, b, 0, false);
  r = __builtin_amdgcn_cvt_pk_fp8_f32(c, d, r, true);
  return (unsigned)r;
}
DEVFN long mk64(unsigned lo, unsigned hi){
  return (long)(((unsigned long long)hi << 32) | lo);
}

// lane<32: keeps x, receives y's counterpart; verified swap algebra (R7)
DEVFN void plswap(unsigned &x, unsigned &y, int h){
#if __has_builtin(__builtin_amdgcn_permlane32_swap)
  i32x2 r = __builtin_amdgcn_permlane32_swap((int)x, (int)y, false, false);
  x = (unsigned)r[0]; y = (unsigned)r[1];
#else
  unsigned ox = (unsigned)__shfl_xor((int)x, 32);
  unsigned oy = (unsigned)__shfl_xor((int)y, 32);
  unsigned nx = h ? oy : x;
  unsigned ny = h ? y  : ox;
  x = nx; y = ny;
#endif
}

DEVFN void gload16(const char* src, char* lds){
  __builtin_amdgcn_global_load_lds(
      (__attribute__((address_space(1))) void*)src,
      (__attribute__((address_space(3))) void*)lds, 16, 0, 0);
}

constexpr int BB = 16, NQ = 2048, NK = 2048, F = 512, D = 256, FV = 512;

// ---------------- projection + row l2norm -> fp8 outputs ----------------
// Y[m][n] = scale * l2norm_rows( X[m][:] . W[n][:] ), 32 rows/block.
// T14 async-stage: next k-step's X/W preloaded to regs under current MFMA.
// MODE 0: row-major fp8 [row][ND] (wq)
// MODE 1: K frag-image  [b][kt][u][lane][16] (wk)
// MODE 2: V frag-image  [b][kt][fvh][u][lane][16], transposed (wv)
template<int KD, int ND, int MODE>
__global__ __launch_bounds__(256,2) void proj_kernel(const float* __restrict__ X,
                                                     const float* __restrict__ W,
                                                     unsigned char* __restrict__ Y,
                                                     float scale)
{
  constexpr bool TR = (MODE == 2);
  constexpr int NW = ND/4;
  constexpr int AF = TR ? 8 : 2;
  constexpr int BF = TR ? 2 : NW/16;
  __shared__ __align__(16) char xsm[32*80];
  __shared__ __align__(16) char wsm[ND*80];
  __shared__ float wsum[4][32];
  const int tid = threadIdx.x;
  const int lane = tid & 63;
  const int wid = tid >> 6;
  const int q16 = lane & 15;
  const int g = lane >> 4;
  const int row0 = blockIdx.x * 32;
  const int rX = tid >> 3, cX = (tid & 7) * 4;

  f32x4 z4 = {0.f,0.f,0.f,0.f};
  f32x4 acc[AF][BF];
  #pragma unroll
  for (int i=0;i<AF;i++){
    #pragma unroll
    for (int j=0;j<BF;j++) acc[i][j] = z4;
  }

  // preload k0 = 0 into regs
  f32x4 xr = *(const f32x4*)(X + (size_t)(row0+rX)*KD + cX);
  f32x4 wr[ND/32];
  #pragma unroll
  for (int j=0;j<ND/32;j++)
    wr[j] = *(const f32x4*)(W + (size_t)(j*32+rX)*KD + cX);

  for (int k0 = 0; k0 < KD; k0 += 32){
    { // write staged regs -> LDS (bf16, stride 80B)
      u32x2 p; p[0]=cvtpk(xr[0],xr[1]); p[1]=cvtpk(xr[2],xr[3]);
      *(u32x2*)(xsm + rX*80 + cX*2) = p;
    }
    #pragma unroll
    for (int j=0;j<ND/32;j++){
      u32x2 p; p[0]=cvtpk(wr[j][0],wr[j][1]); p[1]=cvtpk(wr[j][2],wr[j][3]);
      *(u32x2*)(wsm + (j*32+rX)*80 + cX*2) = p;
    }
    if (k0 + 32 < KD){ // issue next-step loads; latency hides under MFMA below
      xr = *(const f32x4*)(X + (size_t)(row0+rX)*KD + k0+32 + cX);
      #pragma unroll
      for (int j=0;j<ND/32;j++)
        wr[j] = *(const f32x4*)(W + (size_t)(j*32+rX)*KD + k0+32 + cX);
    }
    __syncthreads();
    if constexpr (!TR){
      bf16x8 a[2], bb[BF];
      #pragma unroll
      for (int mi=0;mi<2;mi++)  a[mi]  = as_bf(*(const u32x4*)(xsm + (16*mi+q16)*80 + g*16));
      #pragma unroll
      for (int ni=0;ni<BF;ni++) bb[ni] = as_bf(*(const u32x4*)(wsm + (wid*NW + 16*ni + q16)*80 + g*16));
      #pragma unroll
      for (int mi=0;mi<2;mi++){
        #pragma unroll
        for (int ni=0;ni<BF;ni++)
          acc[mi][ni] = __builtin_amdgcn_mfma_f32_16x16x32_bf16(a[mi], bb[ni], acc[mi][ni], 0,0,0);
      }
    } else {
      bf16x8 a[8], bb[2];
      #pragma unroll
      for (int ai=0;ai<8;ai++) a[ai] = as_bf(*(const u32x4*)(wsm + (wid*NW + 16*ai + q16)*80 + g*16));
      #pragma unroll
      for (int ci=0;ci<2;ci++) bb[ci] = as_bf(*(const u32x4*)(xsm + (16*ci+q16)*80 + g*16));
      #pragma unroll
      for (int ai=0;ai<8;ai++){
        #pragma unroll
        for (int ci=0;ci<2;ci++)
          acc[ai][ci] = __builtin_amdgcn_mfma_f32_16x16x32_bf16(a[ai], bb[ci], acc[ai][ci], 0,0,0);
      }
    }
    __syncthreads();
  }

  if constexpr (!TR){
    float part[2][4];
    #pragma unroll
    for (int mi=0;mi<2;mi++){
      #pragma unroll
      for (int r=0;r<4;r++){
        float s=0.f;
        #pragma unroll
        for (int ni=0;ni<BF;ni++){ float v=acc[mi][ni][r]; s += v*v; }
        part[mi][r]=s;
      }
    }
    #pragma unroll
    for (int m=1;m<16;m<<=1){
      #pragma unroll
      for (int mi=0;mi<2;mi++){
        #pragma unroll
        for (int r=0;r<4;r++) part[mi][r] += __shfl_xor(part[mi][r], m);
      }
    }
    if (q16 == 0){
      #pragma unroll
      for (int mi=0;mi<2;mi++){
        #pragma unroll
        for (int r=0;r<4;r++) wsum[wid][16*mi + 4*g + r] = part[mi][r];
      }
    }
    __syncthreads();
    #pragma unroll
    for (int mi=0;mi<2;mi++){
      #pragma unroll
      for (int r=0;r<4;r++){
        int m = 16*mi + 4*g + r;
        float tot = wsum[0][m]+wsum[1][m]+wsum[2][m]+wsum[3][m];
        float inv = scale / fmaxf(sqrtf(tot), 1e-12f);
        int row = row0 + m;
        #pragma unroll
        for (int ni=0;ni<BF;ni++){
          int col = wid*NW + 16*ni + q16;
          unsigned char vb = f2fp8(acc[mi][ni][r]*inv);
          if constexpr (MODE == 0){
            Y[(size_t)row*ND + col] = vb;
          } else {
            int b2 = row >> 11, kv = row & 2047;
            int kt = kv >> 5, mm = kv & 31;
            int u = col >> 5, dd = col & 31;
            int s = ((dd>>4)<<3) | (dd&7);
            int l = mm + ((dd>>3)&1)*32;
            Y[((((size_t)b2*64 + kt)*8 + u)*64 + l)*16 + s] = vb;
          }
        }
      }
    }
  } else {
    float pp[2];
    #pragma unroll
    for (int ci=0;ci<2;ci++){
      float s=0.f;
      #pragma unroll
      for (int ai=0;ai<8;ai++){
        #pragma unroll
        for (int r=0;r<4;r++){ float v=acc[ai][ci][r]; s += v*v; }
      }
      pp[ci]=s;
    }
    #pragma unroll
    for (int ci=0;ci<2;ci++){
      pp[ci] += __shfl_xor(pp[ci],16);
      pp[ci] += __shfl_xor(pp[ci],32);
    }
    if (lane < 16){ wsum[wid][lane] = pp[0]; wsum[wid][16+lane] = pp[1]; }
    __syncthreads();
    #pragma unroll
    for (int ci=0;ci<2;ci++){
      int m = 16*ci + q16;
      float tot = wsum[0][m]+wsum[1][m]+wsum[2][m]+wsum[3][m];
      float inv = scale / fmaxf(sqrtf(tot), 1e-12f);
      int grow = row0 + m;
      int b2 = grow >> 11;
      int kv = grow & 2047;
      int kt = kv >> 5, kl = kv & 31;
      int s = ((kl>>4)<<3) | (kl&7);
      int lofs = ((kl>>3)&1)*32;
      #pragma unroll
      for (int ai=0;ai<8;ai++){
        #pragma unroll
        for (int r=0;r<4;r++){
          int n = wid*NW + 16*ai + 4*g + r;
          int fvh = n >> 8, u = (n>>5)&7, mm = n & 31;
          unsigned char vb = f2fp8(acc[ai][ci][r]*inv);
          Y[(((((size_t)b2*64 + kt)*2 + fvh)*8 + u)*64 + (mm + lofs))*16 + s] = vb;
        }
      }
    }
  }
}

// ---------------- fused attention (v8: fp8, 2 blocks/CU for phase overlap) -------
// 512 blocks = 16 b x 32 qblk(64 q). 256 thr = 4 waves; wave = (qs, fvh):
// 32 q rows, 256 fv cols. kv-tile 32, dbuf fragpair-major LDS (48KB),
// 1 barrier/tile. Two independent blocks per CU overlap softmax/MFMA phases.
__global__ __launch_bounds__(256,2) void attn_kernel(const float* __restrict__ query,
    const unsigned char* __restrict__ wq8, const unsigned char* __restrict__ k8,
    const unsigned char* __restrict__ v8, float* __restrict__ out)
{
  // K dbuf 2x8K @0 | V dbuf 2x16K @16384 (48K) ; epilogue reuses 32K.
  __shared__ __align__(16) char smem[65536];
  const int tid = threadIdx.x, lane = tid & 63, wid = tid >> 6;
  const int l31 = lane & 31, h = lane >> 5;
  const int qs = wid & 1, fvh = wid >> 1;
  const int bid = blockIdx.x;
  const int lb = (bid & 7)*64 + (bid >> 3);   // XCD chunk swizzle, 512 = 8*64 bijective
  const int b = lb >> 5;
  const int qblk = lb & 31;
  const int q0 = qblk*64;

  const char* ksrc = (const char*)(k8 + (size_t)b*524288)  + lane*16;
  const char* vsrc = (const char*)(v8 + (size_t)b*1048576) + lane*16;

  #define STAGE(T, CUR) do{                                                       \
    gload16(ksrc + (size_t)(T)*8192  +        wid*1024,                           \
            smem + (CUR)*8192 +        wid*1024);                                 \
    gload16(ksrc + (size_t)(T)*8192  + 4096 + wid*1024,                           \
            smem + (CUR)*8192 + 4096 + wid*1024);                                 \
    gload16(vsrc + (size_t)(T)*16384 +         wid*1024,                          \
            smem + 16384 + (CUR)*16384 +         wid*1024);                       \
    gload16(vsrc + (size_t)(T)*16384 +  4096 + wid*1024,                          \
            smem + 16384 + (CUR)*16384 +  4096 + wid*1024);                       \
    gload16(vsrc + (size_t)(T)*16384 +  8192 + wid*1024,                          \
            smem + 16384 + (CUR)*16384 +  8192 + wid*1024);                       \
    gload16(vsrc + (size_t)(T)*16384 + 12288 + wid*1024,                          \
            smem + 16384 + (CUR)*16384 + 12288 + wid*1024);                       \
  }while(0)

  STAGE(0, 0);

  // Q hoist: fp8 B-frags [16 c][32 q]: lane q=l31, bytes d = c*16 + h*8 ..+8
  unsigned long long qf[16];
  {
    const unsigned char* qb = wq8 + ((size_t)b*NQ + q0 + qs*32 + l31)*D;
    #pragma unroll
    for (int c=0;c<16;c++) qf[c] = *(const unsigned long long*)(qb + c*16 + h*8);
  }

  f32x16 z16;
  #pragma unroll
  for (int i=0;i<16;i++) z16[i]=0.f;
  f32x16 o[8];
  #pragma unroll
  for (int i=0;i<8;i++) o[i]=z16;
  float ssum = 0.f;
  const float c2 = 0.0625f * 1.4426950408889634f / 64.0f;   // temp*log2e / (8*8)

  __syncthreads();

  #define BODY(T, CUR) do{                                                          \
    if ((T) < 63) STAGE((T)+1, (CUR)^1);                                            \
    const char* kb = smem + (CUR)*8192;                                             \
    const char* vb = smem + 16384 + (CUR)*16384;                                    \
    f32x16 S = z16;                                                                 \
    __builtin_amdgcn_s_setprio(1);                                                  \
    _Pragma("unroll")                                                               \
    for (int u=0;u<8;u++){                                                          \
      u32x4 kk = *(const u32x4*)(kb + u*1024 + lane*16);                            \
      S = __builtin_amdgcn_mfma_f32_32x32x16_fp8_fp8(mk64(kk[0],kk[1]),             \
            (long)qf[2*u],   S, 0,0,0);                                             \
      S = __builtin_amdgcn_mfma_f32_32x32x16_fp8_fp8(mk64(kk[2],kk[3]),             \
            (long)qf[2*u+1], S, 0,0,0);                                             \
    }                                                                               \
    __builtin_amdgcn_s_setprio(0);                                                  \
    float p[16];                                                                    \
    _Pragma("unroll")                                                               \
    for (int r=0;r<16;r++) p[r] = exp2_hw(S[r]*c2);                                 \
    float s2[8];                                                                    \
    _Pragma("unroll")                                                               \
    for (int j=0;j<8;j++) s2[j] = p[2*j] + p[2*j+1];                                \
    float s4a = (s2[0]+s2[1]) + (s2[2]+s2[3]);                                      \
    float s4b = (s2[4]+s2[5]) + (s2[6]+s2[7]);                                      \
    ssum += s4a + s4b;                                                              \
    unsigned d0 = pk4_fp8(p[0],p[1],p[2],p[3]);     /* kv 4h+0..3   */              \
    unsigned d1 = pk4_fp8(p[4],p[5],p[6],p[7]);     /* kv 8+4h..    */              \
    unsigned d2 = pk4_fp8(p[8],p[9],p[10],p[11]);   /* kv 16+4h..   */              \
    unsigned d3 = pk4_fp8(p[12],p[13],p[14],p[15]); /* kv 24+4h..   */              \
    plswap(d0, d1, h);  plswap(d2, d3, h);                                          \
    long P0 = mk64(d0, d1);   /* chunk0: kv 8h..8h+7  */                            \
    long P1 = mk64(d2, d3);   /* chunk1: kv 16+8h..   */                            \
    __builtin_amdgcn_s_setprio(1);                                                  \
    _Pragma("unroll")                                                               \
    for (int u=0;u<8;u++){                                                          \
      u32x4 vv = *(const u32x4*)(vb + (fvh*8+u)*1024 + lane*16);                    \
      o[u] = __builtin_amdgcn_mfma_f32_32x32x16_fp8_fp8(mk64(vv[0],vv[1]), P0,      \
                                                        o[u], 0,0,0);               \
      o[u] = __builtin_amdgcn_mfma_f32_32x32x16_fp8_fp8(mk64(vv[2],vv[3]), P1,      \
                                                        o[u], 0,0,0);               \
    }                                                                               \
    __builtin_amdgcn_s_setprio(0);                                                  \
    __syncthreads();                                                                \
  }while(0)

  for (int tt = 0; tt < 64; tt += 2){
    BODY(tt,   0);
    BODY(tt+1, 1);
  }
  #undef BODY
  #undef STAGE

  // epilogue: scale by 1/(8*ssum) (V scaled x8), transpose via LDS, +query, store.
  ssum += __shfl_xor(ssum, 32);
  const float inv = 1.f/(8.f*ssum);
  #pragma unroll
  for (int i=0;i<8;i++){
    #pragma unroll
    for (int r=0;r<16;r++) o[i][r] *= inv;
  }

  char* wsc = smem + qs*16384;   // [32 q][128 fv] f32 per qs (post-barrier reuse)
  union U16 { f32x16 v; f32x4 q4[4]; };
  const int swz = (l31 & 7) << 4;
  #pragma unroll
  for (int phase=0; phase<2; ++phase){
    if (fvh == phase){
      #pragma unroll
      for (int hf=0; hf<2; ++hf){
        #pragma unroll
        for (int fc2=0; fc2<4; ++fc2){
          U16 u; u.v = o[hf*4+fc2];
          #pragma unroll
          for (int k=0;k<4;k++){
            *(f32x4*)(wsc + l31*512 + ((fc2*128 + k*32 + h*16) ^ swz)) = u.q4[k];
          }
        }
        #pragma unroll
        for (int p2=0;p2<16;p2++){
          int qr = p2*2 + h;
          f32x4 v = *(const f32x4*)(wsc + qr*512 + ((l31*16) ^ ((qr&7)<<4)));
          size_t row = (size_t)b*NQ + q0 + qs*32 + qr;
          int col = fvh*256 + hf*128 + l31*4;
          f32x4 qv = *(const f32x4*)(query + row*F + col);
          #pragma unroll
          for (int e=0;e<4;e++) v[e] += qv[e];
          *(f32x4*)(out + row*F + col) = v;
        }
      }
    }
    __syncthreads();
  }
}

extern "C" void kernel_launch(void* const* d_in, const int* in_sizes, int n_in,
                              void* d_out, int out_size, void* d_ws, size_t ws_size,
                              hipStream_t stream)
{
  const float* query = (const float*)d_in[0];
  const float* key   = (const float*)d_in[1];
  const float* value = (const float*)d_in[2];
  const float* WQ    = (const float*)d_in[3];
  const float* WK    = (const float*)d_in[4];
  const float* WV    = (const float*)d_in[5];
  float* out = (float*)d_out;

  unsigned char* wq8 = (unsigned char*)d_ws;                 // [B*NQ][256] fp8, 8MB
  unsigned char* k8  = wq8 + (size_t)BB*NQ*D;                // K frag-image, 8MB
  unsigned char* v8  = k8  + (size_t)BB*NK*D;                // V frag-image, 8MB

  dim3 blk(256);
  proj_kernel<512,256,0><<<1024, blk, 0, stream>>>(query, WQ, wq8, 8.0f);
  proj_kernel<256,256,1><<<1024, blk, 0, stream>>>(key,   WK, k8,  8.0f);
  proj_kernel<256,512,2><<<1024, blk, 0, stream>>>(value, WV, v8,  8.0f);
  attn_kernel<<<512, blk, 0, stream>>>(query, wq8, k8, v8, out);
}